// Round 1
// baseline (495.757 us; speedup 1.0000x reference)
//
#include <hip/hip_runtime.h>

// ClusteredLinformerAttention — MI355X bf16-MFMA pipeline, round 1 (correctness-first).
// B=8 N=4096 D=512 H=8 R=256 DEPTH=64. All heavy matmuls on v_mfma_f32_16x16x32_bf16,
// fp32 accumulation. Verified fragment layouts (learn_hip m89/m120):
//   A[m=lane&15][k=quad*8+j], B[k=quad*8+j][n=lane&15], C/D: col=lane&15, row=quad*4+reg.

typedef __bf16 bf16;
typedef __attribute__((ext_vector_type(8))) __bf16 bf16x8;
typedef __attribute__((ext_vector_type(4))) float floatx4;

#define MFMA16(a, b, c) __builtin_amdgcn_mfma_f32_16x16x32_bf16((a), (b), (c), 0, 0, 0)

static __device__ __forceinline__ unsigned short bf_bits(float f) {
  unsigned u = __builtin_bit_cast(unsigned, f);
  u += 0x7fffu + ((u >> 16) & 1u);   // RNE
  return (unsigned short)(u >> 16);
}
static __device__ __forceinline__ bf16 f2bf(float f) {
  unsigned short s = bf_bits(f);
  return __builtin_bit_cast(bf16, s);
}

// ---------------------------------------------------------------------------
// Prep: dst[n*K + k] = bf16(src[k*Nc + n]); z-batched for E/F per-head slices.
// ---------------------------------------------------------------------------
__global__ void transpose_cvt_kernel(const float* __restrict__ src, bf16* __restrict__ dst,
                                     int K, int Nc, long src_z, long dst_z) {
  src += (long)blockIdx.z * src_z;
  dst += (long)blockIdx.z * dst_z;
  __shared__ float tile[32][33];
  const int k0 = blockIdx.x * 32, n0 = blockIdx.y * 32;
  const int tx = threadIdx.x, ty = threadIdx.y;   // (32, 8)
#pragma unroll
  for (int i = ty; i < 32; i += 8)
    tile[i][tx] = src[(long)(k0 + i) * Nc + n0 + tx];
  __syncthreads();
#pragma unroll
  for (int i = ty; i < 32; i += 8)
    dst[(long)(n0 + i) * K + k0 + tx] = f2bf(tile[tx][i]);
}

// ---------------------------------------------------------------------------
// 128x128-tile GEMM, K=512, C = A(M,512) * Bt(N,512)^T.
// MODE 0: A fp32 (x), output split-write q/k/v bf16 (N=1536).
// MODE 1: A bf16 (attn concat), output fp32 + bias (N=512).
// Block 256 thr = 4 waves in 2x2; each wave 64x64 = 4x4 MFMA tiles.
// ---------------------------------------------------------------------------
template <int MODE>
__global__ __launch_bounds__(256) void gemm128_kernel(
    const float* __restrict__ Af, const bf16* __restrict__ Ab, const bf16* __restrict__ Bt,
    bf16* __restrict__ oq, bf16* __restrict__ ok, bf16* __restrict__ ov,
    float* __restrict__ of, const float* __restrict__ bias) {
  __shared__ bf16 As[128][72];   // +8 pad, row stride 144B (16B-aligned)
  __shared__ bf16 Bs[128][72];
  const int m0 = blockIdx.x * 128, n0 = blockIdx.y * 128;
  const int t = threadIdx.x;
  const int w = t >> 6, l = t & 63, quad = l >> 4, lc = l & 15;
  const int wr = w >> 1, wc = w & 1;
  floatx4 acc[4][4] = {};
  for (int k0 = 0; k0 < 512; k0 += 64) {
    if (MODE == 0) {
#pragma unroll
      for (int u = 0; u < 8; ++u) {           // 128x64 fp32 -> bf16
        int f4 = u * 256 + t, row = f4 >> 4, c4 = (f4 & 15) << 2;
        const float4 v = *(const float4*)(Af + (long)(m0 + row) * 512 + k0 + c4);
        ushort4 s;
        s.x = bf_bits(v.x); s.y = bf_bits(v.y); s.z = bf_bits(v.z); s.w = bf_bits(v.w);
        *(ushort4*)&As[row][c4] = s;
      }
    } else {
#pragma unroll
      for (int u = 0; u < 4; ++u) {           // 128x64 bf16, 16B chunks
        int id = u * 256 + t, row = id >> 3, c8 = (id & 7) << 3;
        *(bf16x8*)&As[row][c8] = *(const bf16x8*)(Ab + (long)(m0 + row) * 512 + k0 + c8);
      }
    }
#pragma unroll
    for (int u = 0; u < 4; ++u) {
      int id = u * 256 + t, row = id >> 3, c8 = (id & 7) << 3;
      *(bf16x8*)&Bs[row][c8] = *(const bf16x8*)(Bt + (long)(n0 + row) * 512 + k0 + c8);
    }
    __syncthreads();
#pragma unroll
    for (int kk = 0; kk < 64; kk += 32) {
      bf16x8 af[4], bfr[4];
#pragma unroll
      for (int mt = 0; mt < 4; ++mt)
        af[mt] = *(const bf16x8*)&As[wr * 64 + mt * 16 + lc][kk + quad * 8];
#pragma unroll
      for (int nt = 0; nt < 4; ++nt)
        bfr[nt] = *(const bf16x8*)&Bs[wc * 64 + nt * 16 + lc][kk + quad * 8];
#pragma unroll
      for (int mt = 0; mt < 4; ++mt)
#pragma unroll
        for (int nt = 0; nt < 4; ++nt)
          acc[mt][nt] = MFMA16(af[mt], bfr[nt], acc[mt][nt]);
    }
    __syncthreads();
  }
  if (MODE == 0) {
    const int which = n0 >> 9, nb = n0 & 511;   // block never straddles a 512 boundary
    bf16* dst = which == 0 ? oq : (which == 1 ? ok : ov);
#pragma unroll
    for (int mt = 0; mt < 4; ++mt)
#pragma unroll
      for (int nt = 0; nt < 4; ++nt)
#pragma unroll
        for (int i = 0; i < 4; ++i) {
          int row = m0 + wr * 64 + mt * 16 + quad * 4 + i;
          int col = nb + wc * 64 + nt * 16 + lc;
          dst[(long)row * 512 + col] = f2bf(acc[mt][nt][i]);
        }
  } else {
#pragma unroll
    for (int mt = 0; mt < 4; ++mt)
#pragma unroll
      for (int nt = 0; nt < 4; ++nt)
#pragma unroll
        for (int i = 0; i < 4; ++i) {
          int row = m0 + wr * 64 + mt * 16 + quad * 4 + i;
          int col = n0 + wc * 64 + nt * 16 + lc;
          of[(long)row * 512 + col] = acc[mt][nt][i] + bias[col];
        }
  }
}

// ---------------------------------------------------------------------------
// Low-rank projection: kp[b,h,r,d] = sum_n k[b,h,n,d] * E[h,n,r]  (z=0)
//                      vpT[b,h,d,r] = sum_n v[b,h,n,d] * F[h,n,r] (z=1, pre-transposed)
// A = E^T from pre-transposed global (H,R,N) bf16, fragments direct from global.
// B = K/V tile, LDS-transposed (small: 64x32 per step). 4 n-chunks, atomic epilogue.
// ---------------------------------------------------------------------------
__global__ __launch_bounds__(256) void proj_kernel(
    const bf16* __restrict__ Et_g, const bf16* __restrict__ Ft_g,
    const bf16* __restrict__ kb, const bf16* __restrict__ vb,
    float* __restrict__ kp, float* __restrict__ vpT) {
  const int z = blockIdx.z;
  const bf16* Em = z ? Ft_g : Et_g;
  const bf16* src = z ? vb : kb;
  float* out = z ? vpT : kp;
  const int bh = blockIdx.y, b = bh >> 3, h = bh & 7;
  const int nbase = blockIdx.x * 1024;
  __shared__ bf16 Kt[64][40];   // [d][n_local], stride 80B
  const int t = threadIdx.x;
  const int w = t >> 6, l = t & 63, quad = l >> 4, lc = l & 15;
  const int sn = t & 31, sd = t >> 5;   // staging: 32 n-rows x 8 d-groups
  floatx4 acc[4][4] = {};
  const bf16* ebase = Em + (long)h * 256 * 4096 + nbase;
  for (int it = 0; it < 32; ++it) {
    const int nn0 = it * 32;
    bf16x8 kv = *(const bf16x8*)(src + (long)(b * 4096 + nbase + nn0 + sn) * 512 + h * 64 + sd * 8);
    __syncthreads();   // previous iteration's Kt reads done
#pragma unroll
    for (int j = 0; j < 8; ++j) Kt[sd * 8 + j][sn] = kv[j];
    __syncthreads();
    bf16x8 af[4], bfr[4];
#pragma unroll
    for (int mt = 0; mt < 4; ++mt)   // A-frag direct from (H,R,N): r = w*64+mt*16+lc
      af[mt] = *(const bf16x8*)(ebase + (long)(w * 64 + mt * 16 + lc) * 4096 + nn0 + quad * 8);
#pragma unroll
    for (int nt = 0; nt < 4; ++nt)
      bfr[nt] = *(const bf16x8*)&Kt[nt * 16 + lc][quad * 8];
#pragma unroll
    for (int mt = 0; mt < 4; ++mt)
#pragma unroll
      for (int nt = 0; nt < 4; ++nt)
        acc[mt][nt] = MFMA16(af[mt], bfr[nt], acc[mt][nt]);
  }
  float* obase = out + (long)bh * (256 * 64);
#pragma unroll
  for (int mt = 0; mt < 4; ++mt)
#pragma unroll
    for (int nt = 0; nt < 4; ++nt)
#pragma unroll
      for (int i = 0; i < 4; ++i) {
        int r = w * 64 + mt * 16 + quad * 4 + i;
        int d = nt * 16 + lc;
        long idx = z ? ((long)d * 256 + r) : ((long)r * 64 + d);
        atomicAdd(obase + idx, acc[mt][nt][i]);
      }
}

// ---------------------------------------------------------------------------
// Attention: per (b,h, 128-row tile): S = q*kp^T/8 ; softmax over R=256 ; O = P*vp.
// 512 thr = 8 waves, each owns 16 rows. kp and vpT share one LDS union (phase-
// disjoint). P round-trips through a 32-col LDS chunk (C-layout -> A-layout).
// ---------------------------------------------------------------------------
__global__ __launch_bounds__(512) void attn_kernel(
    const bf16* __restrict__ qb, const float* __restrict__ kp,
    const float* __restrict__ vpT, bf16* __restrict__ ao) {
  const int bx = blockIdx.x, h = blockIdx.y, b = blockIdx.z;
  const int bh = b * 8 + h;
  __shared__ __align__(16) char smem_u[256 * 72 * 2];   // 36,864B >= 64*264*2
  __shared__ bf16 Pc[128][40];
  bf16(*kpl)[72] = (bf16(*)[72])smem_u;
  bf16(*vtl)[264] = (bf16(*)[264])smem_u;
  const int t = threadIdx.x;
  const int w = t >> 6, l = t & 63, quad = l >> 4, lc = l & 15;

  {  // stage kp (256x64 fp32 -> bf16), coalesced
    int r = t >> 1, c0 = (t & 1) * 32;
    const float* p = kp + (long)bh * (256 * 64) + (long)r * 64 + c0;
#pragma unroll
    for (int u = 0; u < 8; ++u) {
      float4 v = *(const float4*)(p + u * 4);
      ushort4 s;
      s.x = bf_bits(v.x); s.y = bf_bits(v.y); s.z = bf_bits(v.z); s.w = bf_bits(v.w);
      *(ushort4*)&kpl[r][c0 + u * 4] = s;
    }
  }
  __syncthreads();

  // GEMM-1: scores. A-frags (q) direct from global bf16.
  const long qrow = (long)(b * 4096 + bx * 128 + w * 16 + lc) * 512 + h * 64;
  floatx4 acc[16] = {};
#pragma unroll
  for (int kk = 0; kk < 64; kk += 32) {
    bf16x8 a = *(const bf16x8*)(qb + qrow + kk + quad * 8);
#pragma unroll
    for (int nt = 0; nt < 16; ++nt) {
      bf16x8 bfr = *(const bf16x8*)&kpl[nt * 16 + lc][kk + quad * 8];
      acc[nt] = MFMA16(a, bfr, acc[nt]);
    }
  }
  __syncthreads();   // all waves done reading kpl; union becomes vpT

  {  // stage vpT (64x256 fp32 -> bf16), coalesced (already transposed in global)
    int d = t >> 3, c0 = (t & 7) * 32;
    const float* p = vpT + (long)bh * (64 * 256) + (long)d * 256 + c0;
#pragma unroll
    for (int u = 0; u < 8; ++u) {
      float4 v = *(const float4*)(p + u * 4);
      ushort4 s;
      s.x = bf_bits(v.x); s.y = bf_bits(v.y); s.z = bf_bits(v.z); s.w = bf_bits(v.w);
      *(ushort4*)&vtl[d][c0 + u * 4] = s;
    }
  }

  // softmax over R in registers; row stats via 16-lane xor-shuffles (C-layout:
  // lane (quad,c) holds rows quad*4+i at cols c+16*nt).
  float mx[4] = {-1e30f, -1e30f, -1e30f, -1e30f};
#pragma unroll
  for (int nt = 0; nt < 16; ++nt)
#pragma unroll
    for (int i = 0; i < 4; ++i) {
      acc[nt][i] *= 0.125f;   // 1/sqrt(64)
      mx[i] = fmaxf(mx[i], acc[nt][i]);
    }
#pragma unroll
  for (int m = 1; m <= 8; m <<= 1)
#pragma unroll
    for (int i = 0; i < 4; ++i) mx[i] = fmaxf(mx[i], __shfl_xor(mx[i], m, 64));
  float sm[4] = {0.f, 0.f, 0.f, 0.f};
#pragma unroll
  for (int nt = 0; nt < 16; ++nt)
#pragma unroll
    for (int i = 0; i < 4; ++i) {
      float p = __expf(acc[nt][i] - mx[i]);
      acc[nt][i] = p;
      sm[i] += p;
    }
#pragma unroll
  for (int m = 1; m <= 8; m <<= 1)
#pragma unroll
    for (int i = 0; i < 4; ++i) sm[i] += __shfl_xor(sm[i], m, 64);
  float inv[4];
#pragma unroll
  for (int i = 0; i < 4; ++i) inv[i] = 1.0f / sm[i];
  __syncthreads();   // vtl staged

  // GEMM-2: O = P*vp, P chunked through LDS (32 r-cols per chunk).
  floatx4 acc2[4] = {};
  for (int rs = 0; rs < 8; ++rs) {
#pragma unroll
    for (int u = 0; u < 2; ++u) {
      int nt = rs * 2 + u;
#pragma unroll
      for (int i = 0; i < 4; ++i)
        Pc[w * 16 + quad * 4 + i][u * 16 + lc] = f2bf(acc[nt][i] * inv[i]);
    }
    __syncthreads();
    bf16x8 a2 = *(const bf16x8*)&Pc[w * 16 + lc][quad * 8];
#pragma unroll
    for (int nt = 0; nt < 4; ++nt) {
      bf16x8 b2 = *(const bf16x8*)&vtl[nt * 16 + lc][rs * 32 + quad * 8];
      acc2[nt] = MFMA16(a2, b2, acc2[nt]);
    }
    __syncthreads();
  }

#pragma unroll
  for (int nt = 0; nt < 4; ++nt)
#pragma unroll
    for (int i = 0; i < 4; ++i) {
      int row = bx * 128 + w * 16 + quad * 4 + i;
      int d = nt * 16 + lc;
      ao[(long)(b * 4096 + row) * 512 + h * 64 + d] = f2bf(acc2[nt][i]);
    }
}

// ---------------------------------------------------------------------------
extern "C" void kernel_launch(void* const* d_in, const int* in_sizes, int n_in,
                              void* d_out, int out_size, void* d_ws, size_t ws_size,
                              hipStream_t stream) {
  const float* x  = (const float*)d_in[0];
  const float* wq = (const float*)d_in[1];
  const float* wk = (const float*)d_in[2];
  const float* wv = (const float*)d_in[3];
  const float* E  = (const float*)d_in[4];
  const float* F  = (const float*)d_in[5];
  const float* wd = (const float*)d_in[6];
  const float* bd = (const float*)d_in[7];
  float* out = (float*)d_out;

  // workspace layout (bytes); total 144,703,488
  char* ws = (char*)d_ws;
  bf16* q_bf  = (bf16*)(ws + 0);             // 33,554,432
  bf16* k_bf  = (bf16*)(ws + 33554432l);     // 33,554,432
  bf16* v_bf  = (bf16*)(ws + 67108864l);     // 33,554,432
  bf16* Et_g  = (bf16*)(ws + 100663296l);    // 16,777,216  (H,R,N) bf16
  bf16* Ft_g  = (bf16*)(ws + 117440512l);    // 16,777,216
  bf16* Wt    = (bf16*)(ws + 134217728l);    //  1,572,864  (1536,512) [wq^T|wk^T|wv^T]
  bf16* wdT   = (bf16*)(ws + 135790592l);    //    524,288
  float* kp   = (float*)(ws + 136314880l);   //  4,194,304  (B,H,R,64) fp32
  float* vpT  = (float*)(ws + 140509184l);   //  4,194,304  (B,H,64,R) fp32
  bf16* attn_o = k_bf;                       // k dead after proj_kernel

  dim3 tb(32, 8);
  transpose_cvt_kernel<<<dim3(16, 16, 1), tb, 0, stream>>>(wq, Wt, 512, 512, 0, 0);
  transpose_cvt_kernel<<<dim3(16, 16, 1), tb, 0, stream>>>(wk, Wt + 512 * 512, 512, 512, 0, 0);
  transpose_cvt_kernel<<<dim3(16, 16, 1), tb, 0, stream>>>(wv, Wt + 2 * 512 * 512, 512, 512, 0, 0);
  transpose_cvt_kernel<<<dim3(16, 16, 1), tb, 0, stream>>>(wd, wdT, 512, 512, 0, 0);
  transpose_cvt_kernel<<<dim3(128, 8, 8), tb, 0, stream>>>(E, Et_g, 4096, 256,
                                                           4096l * 256, 4096l * 256);
  transpose_cvt_kernel<<<dim3(128, 8, 8), tb, 0, stream>>>(F, Ft_g, 4096, 256,
                                                           4096l * 256, 4096l * 256);
  hipMemsetAsync(kp, 0, 8388608l, stream);   // kp+vpT contiguous

  gemm128_kernel<0><<<dim3(256, 12), 256, 0, stream>>>(x, nullptr, Wt,
                                                       q_bf, k_bf, v_bf, nullptr, nullptr);
  proj_kernel<<<dim3(4, 64, 2), 256, 0, stream>>>(Et_g, Ft_g, k_bf, v_bf, kp, vpT);
  attn_kernel<<<dim3(32, 8, 8), 512, 0, stream>>>(q_bf, kp, vpT, attn_o);
  gemm128_kernel<1><<<dim3(256, 4), 256, 0, stream>>>(nullptr, attn_o, wdT,
                                                      nullptr, nullptr, nullptr, out, bd);
}

// Round 2
// 402.732 us; speedup vs baseline: 1.2310x; 1.2310x over previous
//
#include <hip/hip_runtime.h>

// ClusteredLinformerAttention — round 2: m97-style global_load_lds staging,
// bf16 everywhere, atomic-free projection, swizzled proj LDS transpose.
// B=8 N=4096 D=512 H=8 R=256 DEPTH=64.
// MFMA v_mfma_f32_16x16x32_bf16; layouts (m89/m120):
//   A[m=lane&15][k=quad*8+j], B[k=quad*8+j][n=lane&15], C/D: col=lane&15, row=quad*4+reg.

typedef __bf16 bf16;
typedef __attribute__((ext_vector_type(8))) __bf16 bf16x8;
typedef __attribute__((ext_vector_type(8))) unsigned short ushort8;
typedef __attribute__((ext_vector_type(4))) float floatx4;

#define MFMA16(a, b, c) __builtin_amdgcn_mfma_f32_16x16x32_bf16((a), (b), (c), 0, 0, 0)

static __device__ __forceinline__ unsigned short bf_bits(float f) {
  unsigned u = __builtin_bit_cast(unsigned, f);
  u += 0x7fffu + ((u >> 16) & 1u);   // RNE
  return (unsigned short)(u >> 16);
}
static __device__ __forceinline__ bf16 f2bf(float f) {
  unsigned short s = bf_bits(f);
  return __builtin_bit_cast(bf16, s);
}
static __device__ __forceinline__ float bf2f(bf16 v) {
  unsigned u = (unsigned)__builtin_bit_cast(unsigned short, v) << 16;
  return __builtin_bit_cast(float, u);
}
// async global->LDS, 16B/lane; LDS dest = wave-uniform base + lane*16.
static __device__ __forceinline__ void async_copy16(const void* g, void* l) {
  __builtin_amdgcn_global_load_lds((const __attribute__((address_space(1))) void*)g,
                                   (__attribute__((address_space(3))) void*)l, 16, 0, 0);
}

// ---------------------------------------------------------------------------
// fp32 -> bf16 bulk convert (x). 8 elems/thread, exact-size grid.
// ---------------------------------------------------------------------------
__global__ void cvt_bf16_kernel(const float* __restrict__ src, bf16* __restrict__ dst) {
  long i = ((long)blockIdx.x * 256 + threadIdx.x) * 8;
  float4 a = *(const float4*)(src + i);
  float4 b = *(const float4*)(src + i + 4);
  ushort8 o;
  o[0] = bf_bits(a.x); o[1] = bf_bits(a.y); o[2] = bf_bits(a.z); o[3] = bf_bits(a.w);
  o[4] = bf_bits(b.x); o[5] = bf_bits(b.y); o[6] = bf_bits(b.z); o[7] = bf_bits(b.w);
  *(ushort8*)(dst + i) = o;
}

// ---------------------------------------------------------------------------
// Prep: dst[n*K + k] = bf16(src[k*Nc + n]); z-batched for E/F per-head slices.
// ---------------------------------------------------------------------------
__global__ void transpose_cvt_kernel(const float* __restrict__ src, bf16* __restrict__ dst,
                                     int K, int Nc, long src_z, long dst_z) {
  src += (long)blockIdx.z * src_z;
  dst += (long)blockIdx.z * dst_z;
  __shared__ float tile[32][33];
  const int k0 = blockIdx.x * 32, n0 = blockIdx.y * 32;
  const int tx = threadIdx.x, ty = threadIdx.y;   // (32, 8)
#pragma unroll
  for (int i = ty; i < 32; i += 8)
    tile[i][tx] = src[(long)(k0 + i) * Nc + n0 + tx];
  __syncthreads();
#pragma unroll
  for (int i = ty; i < 32; i += 8)
    dst[(long)(n0 + i) * K + k0 + tx] = f2bf(tile[tx][i]);
}

// ---------------------------------------------------------------------------
// 128x128 GEMM, K=512, C = A(M,512)*Bt(N,512)^T, A bf16 everywhere (m97 style:
// global_load_lds width-16 into unpadded [128][64] LDS, 2-barrier K-loop).
// MODE 0: split-write q/k/v bf16 (grid.x=12). MODE 1: fp32 + bias (grid.x=4).
// Grid: blockIdx.x = n-block (fast) for A-tile L2 reuse, blockIdx.y = m-block.
// ---------------------------------------------------------------------------
template <int MODE>
__global__ __launch_bounds__(256) void gemm128_kernel(
    const bf16* __restrict__ A, const bf16* __restrict__ Bt,
    bf16* __restrict__ oq, bf16* __restrict__ ok, bf16* __restrict__ ov,
    float* __restrict__ of, const float* __restrict__ bias) {
  __shared__ bf16 As[128][64];
  __shared__ bf16 Bs[128][64];
  const int m0 = blockIdx.y * 128, n0 = blockIdx.x * 128;
  const int t = threadIdx.x;
  const int w = t >> 6, l = t & 63, quad = l >> 4, lc = l & 15;
  const int wr = w >> 1, wc = w & 1;
  const int srow = w * 32 + (l >> 3);   // staging row (base; +8/issue)
  const int scol = (l & 7) * 8;
  const bf16* ga = A + (long)(m0 + srow) * 512 + scol;
  const bf16* gb = Bt + (long)(n0 + srow) * 512 + scol;
  floatx4 acc[4][4] = {};
  for (int k0 = 0; k0 < 512; k0 += 64) {
#pragma unroll
    for (int i = 0; i < 4; ++i) {
      async_copy16(ga + k0 + (long)i * 8 * 512, &As[w * 32 + i * 8][0]);
      async_copy16(gb + k0 + (long)i * 8 * 512, &Bs[w * 32 + i * 8][0]);
    }
    __syncthreads();
#pragma unroll
    for (int kk = 0; kk < 64; kk += 32) {
      bf16x8 af[4], bfr[4];
#pragma unroll
      for (int mt = 0; mt < 4; ++mt)
        af[mt] = *(const bf16x8*)&As[wr * 64 + mt * 16 + lc][kk + quad * 8];
#pragma unroll
      for (int nt = 0; nt < 4; ++nt)
        bfr[nt] = *(const bf16x8*)&Bs[wc * 64 + nt * 16 + lc][kk + quad * 8];
#pragma unroll
      for (int mt = 0; mt < 4; ++mt)
#pragma unroll
        for (int nt = 0; nt < 4; ++nt)
          acc[mt][nt] = MFMA16(af[mt], bfr[nt], acc[mt][nt]);
    }
    __syncthreads();
  }
  if (MODE == 0) {
    const int which = n0 >> 9, nb = n0 & 511;
    bf16* dst = which == 0 ? oq : (which == 1 ? ok : ov);
#pragma unroll
    for (int mt = 0; mt < 4; ++mt)
#pragma unroll
      for (int nt = 0; nt < 4; ++nt)
#pragma unroll
        for (int i = 0; i < 4; ++i) {
          int row = m0 + wr * 64 + mt * 16 + quad * 4 + i;
          int col = nb + wc * 64 + nt * 16 + lc;
          dst[(long)row * 512 + col] = f2bf(acc[mt][nt][i]);
        }
  } else {
#pragma unroll
    for (int mt = 0; mt < 4; ++mt)
#pragma unroll
      for (int nt = 0; nt < 4; ++nt)
#pragma unroll
        for (int i = 0; i < 4; ++i) {
          int row = m0 + wr * 64 + mt * 16 + quad * 4 + i;
          int col = n0 + wc * 64 + nt * 16 + lc;
          of[(long)row * 512 + col] = acc[mt][nt][i] + bias[col];
        }
  }
}

// ---------------------------------------------------------------------------
// Projection (atomic-free, 4 n-chunk partials in bf16):
//  z=0: kp_part[nc][bh][r][d]  = sum_n k[b,n,h,d] * E[h,n,r]   (A=Et big, B=Kt small)
//  z=1: vp_part[nc][bh][d][r]  = sum_n v[b,n,h,d] * F[h,n,r]   (A=Vt small, B=Ft big)
// Big side (256xk) via global_load_lds; small side LDS-transposed with XOR
// swizzle phys_n = n ^ 8*(d>>3)  (2-way banks on both store & read).
// ---------------------------------------------------------------------------
__global__ __launch_bounds__(256) void proj_kernel(
    const bf16* __restrict__ Et_g, const bf16* __restrict__ Ft_g,
    const bf16* __restrict__ kb, const bf16* __restrict__ vb,
    bf16* __restrict__ kp_part, bf16* __restrict__ vp_part) {
  const int z = blockIdx.z;
  const bf16* Big = z ? Ft_g : Et_g;
  const bf16* src = z ? vb : kb;
  bf16* out = z ? vp_part : kp_part;
  const int bh = blockIdx.y, b = bh >> 3, h = bh & 7;
  const int nbase = blockIdx.x * 1024;
  __shared__ bf16 Eb[256][64];
  __shared__ bf16 Kt[64][72];
  const int t = threadIdx.x;
  const int w = t >> 6, l = t & 63, quad = l >> 4, lc = l & 15;
  const int ecol = (l & 7) * 8;
  const bf16* gE = Big + ((long)h * 256 + w * 64 + (l >> 3)) * 4096 + nbase + ecol;
  const int sn = t >> 3, sq = t & 7;   // small side: rows n = {sn, 32+sn}, d0 = sq*8
  const bf16* gK = src + (long)(b * 4096 + nbase + sn) * 512 + h * 64 + sq * 8;
  floatx4 acc[4][4] = {};
  for (int ks = 0; ks < 16; ++ks) {
    bf16x8 kv0 = *(const bf16x8*)(gK + (long)(ks * 64) * 512);
    bf16x8 kv1 = *(const bf16x8*)(gK + (long)(ks * 64 + 32) * 512);
    __syncthreads();   // previous iteration's LDS reads complete
#pragma unroll
    for (int i = 0; i < 8; ++i)
      async_copy16(gE + ks * 64 + (long)i * 8 * 4096, &Eb[w * 64 + i * 8][0]);
#pragma unroll
    for (int jj = 0; jj < 8; ++jj) Kt[sq * 8 + jj][sn ^ (sq * 8)] = kv0[jj];
#pragma unroll
    for (int jj = 0; jj < 8; ++jj) Kt[sq * 8 + jj][(32 + sn) ^ (sq * 8)] = kv1[jj];
    __syncthreads();   // drains vmcnt (glb->lds) + lgkm (stores)
#pragma unroll
    for (int kk = 0; kk < 64; kk += 32) {
      bf16x8 af[4], bfr[4];
      if (z == 0) {
#pragma unroll
        for (int mt = 0; mt < 4; ++mt)
          af[mt] = *(const bf16x8*)&Eb[w * 64 + mt * 16 + lc][kk + quad * 8];
#pragma unroll
        for (int nt = 0; nt < 4; ++nt) {
          int d = nt * 16 + lc;
          bfr[nt] = *(const bf16x8*)&Kt[d][(kk + quad * 8) ^ ((d >> 3) << 3)];
        }
      } else {
#pragma unroll
        for (int mt = 0; mt < 4; ++mt) {
          int d = mt * 16 + lc;
          af[mt] = *(const bf16x8*)&Kt[d][(kk + quad * 8) ^ ((d >> 3) << 3)];
        }
#pragma unroll
        for (int nt = 0; nt < 4; ++nt)
          bfr[nt] = *(const bf16x8*)&Eb[w * 64 + nt * 16 + lc][kk + quad * 8];
      }
#pragma unroll
      for (int mt = 0; mt < 4; ++mt)
#pragma unroll
        for (int nt = 0; nt < 4; ++nt)
          acc[mt][nt] = MFMA16(af[mt], bfr[nt], acc[mt][nt]);
    }
  }
  bf16* obase = out + ((long)blockIdx.x * 64 + bh) * 16384;
  if (z == 0) {
#pragma unroll
    for (int mt = 0; mt < 4; ++mt)
#pragma unroll
      for (int nt = 0; nt < 4; ++nt)
#pragma unroll
        for (int i = 0; i < 4; ++i) {
          int r = w * 64 + mt * 16 + quad * 4 + i, d = nt * 16 + lc;
          obase[(long)r * 64 + d] = f2bf(acc[mt][nt][i]);
        }
  } else {
#pragma unroll
    for (int mt = 0; mt < 4; ++mt)
#pragma unroll
      for (int nt = 0; nt < 4; ++nt)
#pragma unroll
        for (int i = 0; i < 4; ++i) {
          int d = mt * 16 + quad * 4 + i, r = w * 64 + nt * 16 + lc;
          obase[(long)d * 256 + r] = f2bf(acc[mt][nt][i]);
        }
  }
}

// ---------------------------------------------------------------------------
// Sum 4 bf16 partials -> bf16 (kp and vpT; z selects tensor).
// ---------------------------------------------------------------------------
__global__ void reduce_part_kernel(const bf16* __restrict__ part, bf16* __restrict__ out) {
  part += (long)blockIdx.z * 4194304;
  out += (long)blockIdx.z * 1048576;
  long i = ((long)blockIdx.x * 256 + threadIdx.x) * 8;
  bf16x8 a = *(const bf16x8*)(part + i);
  bf16x8 b = *(const bf16x8*)(part + 1048576 + i);
  bf16x8 c = *(const bf16x8*)(part + 2097152 + i);
  bf16x8 d = *(const bf16x8*)(part + 3145728 + i);
  bf16x8 o;
#pragma unroll
  for (int j = 0; j < 8; ++j)
    o[j] = f2bf(bf2f(a[j]) + bf2f(b[j]) + bf2f(c[j]) + bf2f(d[j]));
  *(bf16x8*)(out + i) = o;
}

// ---------------------------------------------------------------------------
// Attention: per (b,h,128 rows): S = q*kp^T/8; softmax over R=256; O = P*vp.
// bf16 staging (no cvt), double-buffered P chunks (8 barriers in GEMM-2).
// ---------------------------------------------------------------------------
__global__ __launch_bounds__(512) void attn_kernel(
    const bf16* __restrict__ qb, const bf16* __restrict__ kp_bf,
    const bf16* __restrict__ vpT_bf, bf16* __restrict__ ao) {
  const int bx = blockIdx.x, h = blockIdx.y, b = blockIdx.z;
  const int bh = b * 8 + h;
  __shared__ __align__(16) char smem_u[36864];   // kpl 256x72 / vtl 64x264 union
  __shared__ bf16 Pc[2][128][40];
  bf16(*kpl)[72] = (bf16(*)[72])smem_u;
  bf16(*vtl)[264] = (bf16(*)[264])smem_u;
  const int t = threadIdx.x;
  const int w = t >> 6, l = t & 63, quad = l >> 4, lc = l & 15;

  {  // stage kp (256x64 bf16), vectorized
    const bf16* p = kp_bf + (long)bh * 16384;
#pragma unroll
    for (int j = 0; j < 4; ++j) {
      int e = (j * 512 + t) * 8;
      *(bf16x8*)&kpl[e >> 6][e & 63] = *(const bf16x8*)(p + e);
    }
  }
  __syncthreads();

  // GEMM-1: scores; q A-frags direct from global.
  const long qrow = (long)(b * 4096 + bx * 128 + w * 16 + lc) * 512 + h * 64;
  floatx4 acc[16] = {};
#pragma unroll
  for (int kk = 0; kk < 64; kk += 32) {
    bf16x8 a = *(const bf16x8*)(qb + qrow + kk + quad * 8);
#pragma unroll
    for (int nt = 0; nt < 16; ++nt) {
      bf16x8 bfr = *(const bf16x8*)&kpl[nt * 16 + lc][kk + quad * 8];
      acc[nt] = MFMA16(a, bfr, acc[nt]);
    }
  }
  __syncthreads();   // kpl reads done; union becomes vtl

  {  // stage vpT (64x256 bf16)
    const bf16* p = vpT_bf + (long)bh * 16384;
#pragma unroll
    for (int j = 0; j < 4; ++j) {
      int e = (j * 512 + t) * 8;
      *(bf16x8*)&vtl[e >> 8][e & 255] = *(const bf16x8*)(p + e);
    }
  }

  // softmax (C-layout: lane (quad,lc) holds rows quad*4+i, cols lc+16*nt)
  float mx[4] = {-1e30f, -1e30f, -1e30f, -1e30f};
#pragma unroll
  for (int nt = 0; nt < 16; ++nt)
#pragma unroll
    for (int i = 0; i < 4; ++i) {
      acc[nt][i] *= 0.125f;   // 1/sqrt(64)
      mx[i] = fmaxf(mx[i], acc[nt][i]);
    }
#pragma unroll
  for (int m = 1; m <= 8; m <<= 1)
#pragma unroll
    for (int i = 0; i < 4; ++i) mx[i] = fmaxf(mx[i], __shfl_xor(mx[i], m, 64));
  float sm[4] = {0.f, 0.f, 0.f, 0.f};
#pragma unroll
  for (int nt = 0; nt < 16; ++nt)
#pragma unroll
    for (int i = 0; i < 4; ++i) {
      float p = __expf(acc[nt][i] - mx[i]);
      acc[nt][i] = p;
      sm[i] += p;
    }
#pragma unroll
  for (int m = 1; m <= 8; m <<= 1)
#pragma unroll
    for (int i = 0; i < 4; ++i) sm[i] += __shfl_xor(sm[i], m, 64);
  float inv[4];
#pragma unroll
  for (int i = 0; i < 4; ++i) inv[i] = 1.0f / sm[i];

  // GEMM-2: O = P*vp; P chunks (32 r) double-buffered, 1 barrier per chunk.
  floatx4 acc2[4] = {};
  for (int rs = 0; rs < 8; ++rs) {
    const int buf = rs & 1;
#pragma unroll
    for (int u = 0; u < 2; ++u) {
      int nt = rs * 2 + u;
#pragma unroll
      for (int i = 0; i < 4; ++i)
        Pc[buf][w * 16 + quad * 4 + i][u * 16 + lc] = f2bf(acc[nt][i] * inv[i]);
    }
    __syncthreads();   // also covers vtl staging on rs==0
    bf16x8 a2 = *(const bf16x8*)&Pc[buf][w * 16 + lc][quad * 8];
#pragma unroll
    for (int nt = 0; nt < 4; ++nt) {
      bf16x8 b2 = *(const bf16x8*)&vtl[nt * 16 + lc][rs * 32 + quad * 8];
      acc2[nt] = MFMA16(a2, b2, acc2[nt]);
    }
  }

#pragma unroll
  for (int nt = 0; nt < 4; ++nt)
#pragma unroll
    for (int i = 0; i < 4; ++i) {
      int row = bx * 128 + w * 16 + quad * 4 + i;
      int d = nt * 16 + lc;
      ao[(long)(b * 4096 + row) * 512 + h * 64 + d] = f2bf(acc2[nt][i]);
    }
}

// ---------------------------------------------------------------------------
extern "C" void kernel_launch(void* const* d_in, const int* in_sizes, int n_in,
                              void* d_out, int out_size, void* d_ws, size_t ws_size,
                              hipStream_t stream) {
  const float* x  = (const float*)d_in[0];
  const float* wq = (const float*)d_in[1];
  const float* wk = (const float*)d_in[2];
  const float* wv = (const float*)d_in[3];
  const float* E  = (const float*)d_in[4];
  const float* F  = (const float*)d_in[5];
  const float* wd = (const float*)d_in[6];
  const float* bd = (const float*)d_in[7];
  float* out = (float*)d_out;

  // workspace layout (bytes); total 190,840,832
  char* ws = (char*)d_ws;
  bf16* x_bf    = (bf16*)(ws + 0);            // 33,554,432 (dead after QKV -> attn_o)
  bf16* q_bf    = (bf16*)(ws + 33554432l);    // 33,554,432
  bf16* k_bf    = (bf16*)(ws + 67108864l);    // 33,554,432
  bf16* v_bf    = (bf16*)(ws + 100663296l);   // 33,554,432
  bf16* Et_g    = (bf16*)(ws + 134217728l);   // 16,777,216  (H,R,N)
  bf16* Ft_g    = (bf16*)(ws + 150994944l);   // 16,777,216
  bf16* Wt      = (bf16*)(ws + 167772160l);   //  1,572,864  [wq^T|wk^T|wv^T] (n,k)
  bf16* wdT     = (bf16*)(ws + 169345024l);   //    524,288
  bf16* kp_part = (bf16*)(ws + 169869312l);   //  8,388,608  [4][bh][r][d]
  bf16* vp_part = (bf16*)(ws + 178257920l);   //  8,388,608  [4][bh][d][r]
  bf16* kp_bf   = (bf16*)(ws + 186646528l);   //  2,097,152
  bf16* vpT_bf  = (bf16*)(ws + 188743680l);   //  2,097,152
  bf16* attn_o  = x_bf;

  dim3 tb(32, 8);
  cvt_bf16_kernel<<<8192, 256, 0, stream>>>(x, x_bf);
  transpose_cvt_kernel<<<dim3(16, 16, 1), tb, 0, stream>>>(wq, Wt, 512, 512, 0, 0);
  transpose_cvt_kernel<<<dim3(16, 16, 1), tb, 0, stream>>>(wk, Wt + 512 * 512, 512, 512, 0, 0);
  transpose_cvt_kernel<<<dim3(16, 16, 1), tb, 0, stream>>>(wv, Wt + 2 * 512 * 512, 512, 512, 0, 0);
  transpose_cvt_kernel<<<dim3(16, 16, 1), tb, 0, stream>>>(wd, wdT, 512, 512, 0, 0);
  transpose_cvt_kernel<<<dim3(128, 8, 8), tb, 0, stream>>>(E, Et_g, 4096, 256,
                                                           4096l * 256, 4096l * 256);
  transpose_cvt_kernel<<<dim3(128, 8, 8), tb, 0, stream>>>(F, Ft_g, 4096, 256,
                                                           4096l * 256, 4096l * 256);

  gemm128_kernel<0><<<dim3(12, 256), 256, 0, stream>>>(x_bf, Wt, q_bf, k_bf, v_bf,
                                                       nullptr, nullptr);
  proj_kernel<<<dim3(4, 64, 2), 256, 0, stream>>>(Et_g, Ft_g, k_bf, v_bf, kp_part, vp_part);
  reduce_part_kernel<<<dim3(512, 1, 2), 256, 0, stream>>>(kp_part, kp_bf);
  attn_kernel<<<dim3(32, 8, 8), 512, 0, stream>>>(q_bf, kp_bf, vpT_bf, attn_o);
  gemm128_kernel<1><<<dim3(4, 256), 256, 0, stream>>>(attn_o, wdT, nullptr, nullptr, nullptr,
                                                      out, bd);
}

// Round 3
// 390.382 us; speedup vs baseline: 1.2699x; 1.0316x over previous
//
#include <hip/hip_runtime.h>

// ClusteredLinformerAttention — round 3: XCD-aware swizzle for A-tile L2
// locality in both GEMMs, reduce-kernel fused into attention staging,
// batched prep launches. B=8 N=4096 D=512 H=8 R=256 DEPTH=64.
// MFMA v_mfma_f32_16x16x32_bf16; layouts (m89/m120):
//   A[m=lane&15][k=quad*8+j], B[k=quad*8+j][n=lane&15], C/D: col=lane&15, row=quad*4+reg.

typedef __bf16 bf16;
typedef __attribute__((ext_vector_type(8))) __bf16 bf16x8;
typedef __attribute__((ext_vector_type(8))) unsigned short ushort8;
typedef __attribute__((ext_vector_type(4))) float floatx4;

#define MFMA16(a, b, c) __builtin_amdgcn_mfma_f32_16x16x32_bf16((a), (b), (c), 0, 0, 0)

static __device__ __forceinline__ unsigned short bf_bits(float f) {
  unsigned u = __builtin_bit_cast(unsigned, f);
  u += 0x7fffu + ((u >> 16) & 1u);   // RNE
  return (unsigned short)(u >> 16);
}
static __device__ __forceinline__ bf16 f2bf(float f) {
  unsigned short s = bf_bits(f);
  return __builtin_bit_cast(bf16, s);
}
static __device__ __forceinline__ float bf2f(bf16 v) {
  unsigned u = (unsigned)__builtin_bit_cast(unsigned short, v) << 16;
  return __builtin_bit_cast(float, u);
}
// async global->LDS, 16B/lane; LDS dest = wave-uniform base + lane*16.
static __device__ __forceinline__ void async_copy16(const void* g, void* l) {
  __builtin_amdgcn_global_load_lds((const __attribute__((address_space(1))) void*)g,
                                   (__attribute__((address_space(3))) void*)l, 16, 0, 0);
}

// ---------------------------------------------------------------------------
// fp32 -> bf16 bulk convert (x). 8 elems/thread.
// ---------------------------------------------------------------------------
__global__ void cvt_bf16_kernel(const float* __restrict__ src, bf16* __restrict__ dst) {
  long i = ((long)blockIdx.x * 256 + threadIdx.x) * 8;
  float4 a = *(const float4*)(src + i);
  float4 b = *(const float4*)(src + i + 4);
  ushort8 o;
  o[0] = bf_bits(a.x); o[1] = bf_bits(a.y); o[2] = bf_bits(a.z); o[3] = bf_bits(a.w);
  o[4] = bf_bits(b.x); o[5] = bf_bits(b.y); o[6] = bf_bits(b.z); o[7] = bf_bits(b.w);
  *(ushort8*)(dst + i) = o;
}

// ---------------------------------------------------------------------------
// Batched weight transpose: z selects (src,dst). dst[n*512+k] = bf16(src[k*512+n]).
// ---------------------------------------------------------------------------
__global__ void transpose_w4_kernel(const float* __restrict__ wq, const float* __restrict__ wk,
                                    const float* __restrict__ wv, const float* __restrict__ wd,
                                    bf16* __restrict__ Wt, bf16* __restrict__ wdT) {
  const int z = blockIdx.z;
  const float* src = z == 0 ? wq : (z == 1 ? wk : (z == 2 ? wv : wd));
  bf16* dst = z < 3 ? Wt + (long)z * 262144 : wdT;
  __shared__ float tile[32][33];
  const int k0 = blockIdx.x * 32, n0 = blockIdx.y * 32;
  const int tx = threadIdx.x, ty = threadIdx.y;   // (32, 8)
#pragma unroll
  for (int i = ty; i < 32; i += 8)
    tile[i][tx] = src[(long)(k0 + i) * 512 + n0 + tx];
  __syncthreads();
#pragma unroll
  for (int i = ty; i < 32; i += 8)
    dst[(long)(n0 + i) * 512 + k0 + tx] = f2bf(tile[tx][i]);
}

// ---------------------------------------------------------------------------
// E/F transpose, z = tensor*8 + head: dst[(h,r),n] = bf16(src[h,n,r]).
// ---------------------------------------------------------------------------
__global__ void transpose_ef_kernel(const float* __restrict__ E, const float* __restrict__ F,
                                    bf16* __restrict__ Et, bf16* __restrict__ Ft) {
  const int z = blockIdx.z, h = z & 7;
  const float* src = (z < 8 ? E : F) + (long)h * 4096 * 256;
  bf16* dst = (z < 8 ? Et : Ft) + (long)h * 256 * 4096;
  __shared__ float tile[32][33];
  const int k0 = blockIdx.x * 32, n0 = blockIdx.y * 32;   // k0: n-dim(4096), n0: r-dim(256)
  const int tx = threadIdx.x, ty = threadIdx.y;
#pragma unroll
  for (int i = ty; i < 32; i += 8)
    tile[i][tx] = src[(long)(k0 + i) * 256 + n0 + tx];
  __syncthreads();
#pragma unroll
  for (int i = ty; i < 32; i += 8)
    dst[(long)(n0 + i) * 4096 + k0 + tx] = f2bf(tile[tx][i]);
}

// ---------------------------------------------------------------------------
// 128x128 GEMM, K=512, C = A(M,512)*Bt(N,512)^T (m97-style staging).
// XCD swizzle: lin = dispatch index; p = lin&7 (XCD), q = lin>>3;
// m_blk = p*32 + q/NB, n_blk = q%NB -> each XCD owns a contiguous m-band and
// the NB same-A blocks are temporally adjacent on that XCD (A hot in its L2).
// MODE 0: NB=12, split-write q/k/v bf16. MODE 1: NB=4, fp32 + bias.
// ---------------------------------------------------------------------------
template <int MODE>
__global__ __launch_bounds__(256) void gemm128_kernel(
    const bf16* __restrict__ A, const bf16* __restrict__ Bt,
    bf16* __restrict__ oq, bf16* __restrict__ ok, bf16* __restrict__ ov,
    float* __restrict__ of, const float* __restrict__ bias) {
  constexpr int NB = MODE == 0 ? 12 : 4;
  const int lin = blockIdx.x;
  const int p = lin & 7, q = lin >> 3;
  const int m0 = (p * 32 + q / NB) * 128, n0 = (q % NB) * 128;
  __shared__ bf16 As[128][64];
  __shared__ bf16 Bs[128][64];
  const int t = threadIdx.x;
  const int w = t >> 6, l = t & 63, quad = l >> 4, lc = l & 15;
  const int wr = w >> 1, wc = w & 1;
  const int srow = w * 32 + (l >> 3);
  const int scol = (l & 7) * 8;
  const bf16* ga = A + (long)(m0 + srow) * 512 + scol;
  const bf16* gb = Bt + (long)(n0 + srow) * 512 + scol;
  floatx4 acc[4][4] = {};
  for (int k0 = 0; k0 < 512; k0 += 64) {
#pragma unroll
    for (int i = 0; i < 4; ++i) {
      async_copy16(ga + k0 + (long)i * 8 * 512, &As[w * 32 + i * 8][0]);
      async_copy16(gb + k0 + (long)i * 8 * 512, &Bs[w * 32 + i * 8][0]);
    }
    __syncthreads();
#pragma unroll
    for (int kk = 0; kk < 64; kk += 32) {
      bf16x8 af[4], bfr[4];
#pragma unroll
      for (int mt = 0; mt < 4; ++mt)
        af[mt] = *(const bf16x8*)&As[wr * 64 + mt * 16 + lc][kk + quad * 8];
#pragma unroll
      for (int nt = 0; nt < 4; ++nt)
        bfr[nt] = *(const bf16x8*)&Bs[wc * 64 + nt * 16 + lc][kk + quad * 8];
#pragma unroll
      for (int mt = 0; mt < 4; ++mt)
#pragma unroll
        for (int nt = 0; nt < 4; ++nt)
          acc[mt][nt] = MFMA16(af[mt], bfr[nt], acc[mt][nt]);
    }
    __syncthreads();
  }
  if (MODE == 0) {
    const int which = n0 >> 9, nb = n0 & 511;
    bf16* dst = which == 0 ? oq : (which == 1 ? ok : ov);
#pragma unroll
    for (int mt = 0; mt < 4; ++mt)
#pragma unroll
      for (int nt = 0; nt < 4; ++nt)
#pragma unroll
        for (int i = 0; i < 4; ++i) {
          int row = m0 + wr * 64 + mt * 16 + quad * 4 + i;
          int col = nb + wc * 64 + nt * 16 + lc;
          dst[(long)row * 512 + col] = f2bf(acc[mt][nt][i]);
        }
  } else {
#pragma unroll
    for (int mt = 0; mt < 4; ++mt)
#pragma unroll
      for (int nt = 0; nt < 4; ++nt)
#pragma unroll
        for (int i = 0; i < 4; ++i) {
          int row = m0 + wr * 64 + mt * 16 + quad * 4 + i;
          int col = n0 + wc * 64 + nt * 16 + lc;
          of[(long)row * 512 + col] = acc[mt][nt][i] + bias[col];
        }
  }
}

// ---------------------------------------------------------------------------
// Projection (atomic-free, 4 n-chunk bf16 partials):
//  z=0: kp_part[nc][bh][r][d] = sum_n k[b,n,h,d] * E[h,n,r]
//  z=1: vp_part[nc][bh][d][r] = sum_n v[b,n,h,d] * F[h,n,r]
// Big side (E/F^T, 256 x k) via global_load_lds; small side (K/V) LDS-
// transposed with XOR swizzle (2-way max on store & read).
// ---------------------------------------------------------------------------
__global__ __launch_bounds__(256) void proj_kernel(
    const bf16* __restrict__ Et_g, const bf16* __restrict__ Ft_g,
    const bf16* __restrict__ kb, const bf16* __restrict__ vb,
    bf16* __restrict__ kp_part, bf16* __restrict__ vp_part) {
  const int z = blockIdx.z;
  const bf16* Big = z ? Ft_g : Et_g;
  const bf16* src = z ? vb : kb;
  bf16* out = z ? vp_part : kp_part;
  const int bh = blockIdx.y, b = bh >> 3, h = bh & 7;
  const int nbase = blockIdx.x * 1024;
  __shared__ bf16 Eb[256][64];
  __shared__ bf16 Kt[64][72];
  const int t = threadIdx.x;
  const int w = t >> 6, l = t & 63, quad = l >> 4, lc = l & 15;
  const int ecol = (l & 7) * 8;
  const bf16* gE = Big + ((long)h * 256 + w * 64 + (l >> 3)) * 4096 + nbase + ecol;
  const int sn = t >> 3, sq = t & 7;
  const bf16* gK = src + (long)(b * 4096 + nbase + sn) * 512 + h * 64 + sq * 8;
  floatx4 acc[4][4] = {};
  for (int ks = 0; ks < 16; ++ks) {
    bf16x8 kv0 = *(const bf16x8*)(gK + (long)(ks * 64) * 512);
    bf16x8 kv1 = *(const bf16x8*)(gK + (long)(ks * 64 + 32) * 512);
    __syncthreads();   // previous iteration's LDS reads complete
#pragma unroll
    for (int i = 0; i < 8; ++i)
      async_copy16(gE + ks * 64 + (long)i * 8 * 4096, &Eb[w * 64 + i * 8][0]);
#pragma unroll
    for (int jj = 0; jj < 8; ++jj) Kt[sq * 8 + jj][sn ^ (sq * 8)] = kv0[jj];
#pragma unroll
    for (int jj = 0; jj < 8; ++jj) Kt[sq * 8 + jj][(32 + sn) ^ (sq * 8)] = kv1[jj];
    __syncthreads();
#pragma unroll
    for (int kk = 0; kk < 64; kk += 32) {
      bf16x8 af[4], bfr[4];
      if (z == 0) {
#pragma unroll
        for (int mt = 0; mt < 4; ++mt)
          af[mt] = *(const bf16x8*)&Eb[w * 64 + mt * 16 + lc][kk + quad * 8];
#pragma unroll
        for (int nt = 0; nt < 4; ++nt) {
          int d = nt * 16 + lc;
          bfr[nt] = *(const bf16x8*)&Kt[d][(kk + quad * 8) ^ ((d >> 3) << 3)];
        }
      } else {
#pragma unroll
        for (int mt = 0; mt < 4; ++mt) {
          int d = mt * 16 + lc;
          af[mt] = *(const bf16x8*)&Kt[d][(kk + quad * 8) ^ ((d >> 3) << 3)];
        }
#pragma unroll
        for (int nt = 0; nt < 4; ++nt)
          bfr[nt] = *(const bf16x8*)&Eb[w * 64 + nt * 16 + lc][kk + quad * 8];
      }
#pragma unroll
      for (int mt = 0; mt < 4; ++mt)
#pragma unroll
        for (int nt = 0; nt < 4; ++nt)
          acc[mt][nt] = MFMA16(af[mt], bfr[nt], acc[mt][nt]);
    }
  }
  bf16* obase = out + ((long)blockIdx.x * 64 + bh) * 16384;
  if (z == 0) {
#pragma unroll
    for (int mt = 0; mt < 4; ++mt)
#pragma unroll
      for (int nt = 0; nt < 4; ++nt)
#pragma unroll
        for (int i = 0; i < 4; ++i) {
          int r = w * 64 + mt * 16 + quad * 4 + i, d = nt * 16 + lc;
          obase[(long)r * 64 + d] = f2bf(acc[mt][nt][i]);
        }
  } else {
#pragma unroll
    for (int mt = 0; mt < 4; ++mt)
#pragma unroll
      for (int nt = 0; nt < 4; ++nt)
#pragma unroll
        for (int i = 0; i < 4; ++i) {
          int d = mt * 16 + quad * 4 + i, r = w * 64 + nt * 16 + lc;
          obase[(long)d * 256 + r] = f2bf(acc[mt][nt][i]);
        }
  }
}

// ---------------------------------------------------------------------------
// Attention, with partial-reduce fused into LDS staging (sums the 4 proj
// n-chunk partials, fp32 accum then one bf16 round — same numerics as the
// old reduce kernel). Per (b,h,128 rows): S=q*kp^T/8; softmax R=256; O=P*vp.
// ---------------------------------------------------------------------------
__global__ __launch_bounds__(512) void attn_kernel(
    const bf16* __restrict__ qb, const bf16* __restrict__ kp_part,
    const bf16* __restrict__ vp_part, bf16* __restrict__ ao) {
  const int bx = blockIdx.x, h = blockIdx.y, b = blockIdx.z;
  const int bh = b * 8 + h;
  __shared__ __align__(16) char smem_u[36864];   // kpl 256x72 / vtl 64x264 union
  __shared__ bf16 Pc[2][128][40];
  bf16(*kpl)[72] = (bf16(*)[72])smem_u;
  bf16(*vtl)[264] = (bf16(*)[264])smem_u;
  const int t = threadIdx.x;
  const int w = t >> 6, l = t & 63, quad = l >> 4, lc = l & 15;

  {  // stage kp = sum of 4 partials (256x64 bf16)
    const bf16* p = kp_part + (long)bh * 16384;
#pragma unroll
    for (int j = 0; j < 4; ++j) {
      long e = (long)(j * 512 + t) * 8;
      bf16x8 a = *(const bf16x8*)(p + e);
      bf16x8 bb = *(const bf16x8*)(p + 1048576 + e);
      bf16x8 c = *(const bf16x8*)(p + 2097152 + e);
      bf16x8 d = *(const bf16x8*)(p + 3145728 + e);
      bf16x8 o;
#pragma unroll
      for (int jj = 0; jj < 8; ++jj)
        o[jj] = f2bf(bf2f(a[jj]) + bf2f(bb[jj]) + bf2f(c[jj]) + bf2f(d[jj]));
      int e32 = j * 512 + t;
      *(bf16x8*)&kpl[e32 >> 3][(e32 & 7) * 8] = o;
    }
  }
  __syncthreads();

  // GEMM-1: scores; q A-frags direct from global.
  const long qrow = (long)(b * 4096 + bx * 128 + w * 16 + lc) * 512 + h * 64;
  floatx4 acc[16] = {};
#pragma unroll
  for (int kk = 0; kk < 64; kk += 32) {
    bf16x8 a = *(const bf16x8*)(qb + qrow + kk + quad * 8);
#pragma unroll
    for (int nt = 0; nt < 16; ++nt) {
      bf16x8 bfr = *(const bf16x8*)&kpl[nt * 16 + lc][kk + quad * 8];
      acc[nt] = MFMA16(a, bfr, acc[nt]);
    }
  }
  __syncthreads();   // kpl reads done; union becomes vtl

  {  // stage vpT = sum of 4 partials (64x256 bf16)
    const bf16* p = vp_part + (long)bh * 16384;
#pragma unroll
    for (int j = 0; j < 4; ++j) {
      long e = (long)(j * 512 + t) * 8;
      bf16x8 a = *(const bf16x8*)(p + e);
      bf16x8 bb = *(const bf16x8*)(p + 1048576 + e);
      bf16x8 c = *(const bf16x8*)(p + 2097152 + e);
      bf16x8 d = *(const bf16x8*)(p + 3145728 + e);
      bf16x8 o;
#pragma unroll
      for (int jj = 0; jj < 8; ++jj)
        o[jj] = f2bf(bf2f(a[jj]) + bf2f(bb[jj]) + bf2f(c[jj]) + bf2f(d[jj]));
      int e32 = j * 512 + t;
      *(bf16x8*)&vtl[e32 >> 5][(e32 & 31) * 8] = o;
    }
  }

  // softmax (C-layout: lane (quad,lc) holds rows quad*4+i, cols lc+16*nt)
  float mx[4] = {-1e30f, -1e30f, -1e30f, -1e30f};
#pragma unroll
  for (int nt = 0; nt < 16; ++nt)
#pragma unroll
    for (int i = 0; i < 4; ++i) {
      acc[nt][i] *= 0.125f;   // 1/sqrt(64)
      mx[i] = fmaxf(mx[i], acc[nt][i]);
    }
#pragma unroll
  for (int m = 1; m <= 8; m <<= 1)
#pragma unroll
    for (int i = 0; i < 4; ++i) mx[i] = fmaxf(mx[i], __shfl_xor(mx[i], m, 64));
  float sm[4] = {0.f, 0.f, 0.f, 0.f};
#pragma unroll
  for (int nt = 0; nt < 16; ++nt)
#pragma unroll
    for (int i = 0; i < 4; ++i) {
      float pp = __expf(acc[nt][i] - mx[i]);
      acc[nt][i] = pp;
      sm[i] += pp;
    }
#pragma unroll
  for (int m = 1; m <= 8; m <<= 1)
#pragma unroll
    for (int i = 0; i < 4; ++i) sm[i] += __shfl_xor(sm[i], m, 64);
  float inv[4];
#pragma unroll
  for (int i = 0; i < 4; ++i) inv[i] = 1.0f / sm[i];

  // GEMM-2: O = P*vp; P chunks (32 r) double-buffered, 1 barrier per chunk.
  floatx4 acc2[4] = {};
  for (int rs = 0; rs < 8; ++rs) {
    const int buf = rs & 1;
#pragma unroll
    for (int u = 0; u < 2; ++u) {
      int nt = rs * 2 + u;
#pragma unroll
      for (int i = 0; i < 4; ++i)
        Pc[buf][w * 16 + quad * 4 + i][u * 16 + lc] = f2bf(acc[nt][i] * inv[i]);
    }
    __syncthreads();   // also covers vtl staging on rs==0
    bf16x8 a2 = *(const bf16x8*)&Pc[buf][w * 16 + lc][quad * 8];
#pragma unroll
    for (int nt = 0; nt < 4; ++nt) {
      bf16x8 b2 = *(const bf16x8*)&vtl[nt * 16 + lc][rs * 32 + quad * 8];
      acc2[nt] = MFMA16(a2, b2, acc2[nt]);
    }
  }

#pragma unroll
  for (int nt = 0; nt < 4; ++nt)
#pragma unroll
    for (int i = 0; i < 4; ++i) {
      int row = bx * 128 + w * 16 + quad * 4 + i;
      int d = nt * 16 + lc;
      ao[(long)(b * 4096 + row) * 512 + h * 64 + d] = f2bf(acc2[nt][i]);
    }
}

// ---------------------------------------------------------------------------
extern "C" void kernel_launch(void* const* d_in, const int* in_sizes, int n_in,
                              void* d_out, int out_size, void* d_ws, size_t ws_size,
                              hipStream_t stream) {
  const float* x  = (const float*)d_in[0];
  const float* wq = (const float*)d_in[1];
  const float* wk = (const float*)d_in[2];
  const float* wv = (const float*)d_in[3];
  const float* E  = (const float*)d_in[4];
  const float* F  = (const float*)d_in[5];
  const float* wd = (const float*)d_in[6];
  const float* bd = (const float*)d_in[7];
  float* out = (float*)d_out;

  // workspace layout (bytes); total 186,646,528
  char* ws = (char*)d_ws;
  bf16* x_bf    = (bf16*)(ws + 0);            // 33,554,432 (dead after QKV -> attn_o)
  bf16* q_bf    = (bf16*)(ws + 33554432l);    // 33,554,432
  bf16* k_bf    = (bf16*)(ws + 67108864l);    // 33,554,432
  bf16* v_bf    = (bf16*)(ws + 100663296l);   // 33,554,432
  bf16* Et_g    = (bf16*)(ws + 134217728l);   // 16,777,216  (H,R,N)
  bf16* Ft_g    = (bf16*)(ws + 150994944l);   // 16,777,216
  bf16* Wt      = (bf16*)(ws + 167772160l);   //  1,572,864  [wq^T|wk^T|wv^T] (n,k)
  bf16* wdT     = (bf16*)(ws + 169345024l);   //    524,288
  bf16* kp_part = (bf16*)(ws + 169869312l);   //  8,388,608  [4][bh][r][d]
  bf16* vp_part = (bf16*)(ws + 178257920l);   //  8,388,608  [4][bh][d][r]
  bf16* attn_o  = x_bf;

  dim3 tb(32, 8);
  cvt_bf16_kernel<<<8192, 256, 0, stream>>>(x, x_bf);
  transpose_w4_kernel<<<dim3(16, 16, 4), tb, 0, stream>>>(wq, wk, wv, wd, Wt, wdT);
  transpose_ef_kernel<<<dim3(128, 8, 16), tb, 0, stream>>>(E, F, Et_g, Ft_g);

  gemm128_kernel<0><<<3072, 256, 0, stream>>>(x_bf, Wt, q_bf, k_bf, v_bf, nullptr, nullptr);
  proj_kernel<<<dim3(4, 64, 2), 256, 0, stream>>>(Et_g, Ft_g, k_bf, v_bf, kp_part, vp_part);
  attn_kernel<<<dim3(32, 8, 8), 512, 0, stream>>>(q_bf, kp_part, vp_part, attn_o);
  gemm128_kernel<1><<<1024, 256, 0, stream>>>(attn_o, wdT, nullptr, nullptr, nullptr, out, bd);
}